// Round 1
// baseline (760.266 us; speedup 1.0000x reference)
//
#include <hip/hip_runtime.h>

// Problem constants (match reference).
#define NROWS 1048576
#define NC    128
#define EPSF  1e-12f

// ---------------------------------------------------------------------------
// Kernel 1: wave-per-row argmax + confusion-matrix scatter-add.
// Each 64-lane wave owns one row of y_pred [NROWS, 128]:
//   lane i loads float2 at columns {2i, 2i+1}  -> 512 B coalesced per wave.
// Shuffle-reduce (val, idx) with jnp.argmax semantics: larger val wins;
// exact tie -> lower index (first occurrence).
// Lane 0 does one global atomicAdd into conf[y_true[row]*128 + pred].
// ---------------------------------------------------------------------------
__global__ void __launch_bounds__(256) argmax_conf_kernel(
    const float* __restrict__ y_pred,
    const int*   __restrict__ y_true,
    int*         __restrict__ conf,
    int n_rows)
{
    const int tid    = blockIdx.x * blockDim.x + threadIdx.x;
    const int lane   = threadIdx.x & 63;
    const int wave   = tid >> 6;
    const int nwaves = (gridDim.x * blockDim.x) >> 6;

    for (int row = wave; row < n_rows; row += nwaves) {
        const float2 v2 = ((const float2*)(y_pred + (size_t)row * NC))[lane];

        float v;
        int   idx;
        if (v2.y > v2.x) { v = v2.y; idx = 2 * lane + 1; }
        else             { v = v2.x; idx = 2 * lane;     }

        #pragma unroll
        for (int off = 1; off < 64; off <<= 1) {
            float ov = __shfl_xor(v, off, 64);
            int   oi = __shfl_xor(idx, off, 64);
            if (ov > v || (ov == v && oi < idx)) { v = ov; idx = oi; }
        }

        if (lane == 0) {
            const int t = y_true[row];
            atomicAdd(&conf[t * NC + idx], 1);
        }
    }
}

// ---------------------------------------------------------------------------
// Kernel 2: per-class F1 + mean, single 128-thread block.
// Faithful to the reference's gather-index quirk:
//   FP_c = (C-1)*conf[c,1] + conf[c,0]
//   FN_c = (C-1)*conf[1,c] + conf[0,c]
// All arithmetic in f32 with EPS=1e-12, like the jnp reference.
// ---------------------------------------------------------------------------
__global__ void f1_mean_kernel(const int* __restrict__ conf,
                               float* __restrict__ out)
{
    __shared__ float partial[NC];
    const int c = threadIdx.x;

    const float TP = (float)conf[c * NC + c];
    const float FP = (float)(NC - 1) * (float)conf[c * NC + 1] + (float)conf[c * NC + 0];
    const float FN = (float)(NC - 1) * (float)conf[1 * NC + c] + (float)conf[0 * NC + c];

    const float sens = TP / (TP + FN + EPSF);
    const float prec = TP / (TP + FP + EPSF);
    const float f1   = 2.0f * (prec * sens / (prec + sens + EPSF));

    partial[c] = f1;
    __syncthreads();

    #pragma unroll
    for (int s = 64; s > 0; s >>= 1) {
        if (c < s) partial[c] += partial[c + s];
        __syncthreads();
    }

    if (c == 0) out[0] = partial[0] / (float)NC;
}

extern "C" void kernel_launch(void* const* d_in, const int* in_sizes, int n_in,
                              void* d_out, int out_size, void* d_ws, size_t ws_size,
                              hipStream_t stream)
{
    const float* y_pred = (const float*)d_in[0];
    const int*   y_true = (const int*)d_in[1];
    float*       out    = (float*)d_out;
    int*         conf   = (int*)d_ws;   // 128*128*4 = 64 KB of scratch

    const int n_rows = in_sizes[1];     // N = 1048576 (y_true element count)

    // d_ws is poisoned to 0xAA before every timed call — zero the conf matrix.
    hipMemsetAsync(conf, 0, NC * NC * sizeof(int), stream);

    // 8192 blocks x 256 thr = 32768 waves -> 32 rows per wave; 128 waves/CU
    // worth of work keeps all 256 CUs latency-hidden.
    argmax_conf_kernel<<<8192, 256, 0, stream>>>(y_pred, y_true, conf, n_rows);

    f1_mean_kernel<<<1, NC, 0, stream>>>(conf, out);
}

// Round 2
// 683.890 us; speedup vs baseline: 1.1117x; 1.1117x over previous
//
#include <hip/hip_runtime.h>

// Problem constants (match reference).
#define NROWS 1048576
#define NC    128
#define EPSF  1e-12f

// ---------------------------------------------------------------------------
// Kernel 1: quarter-wave-per-row argmax + confusion-matrix scatter-add.
//
// R1 change vs R0: the wave-per-row version spent ~12 DS-pipe ops (shuffles)
// per row -> ~119 us/CU of DS serialization (> 81 us HBM floor). Now each
// 16-lane quarter owns one row: lane q loads float4 at cols [4q..4q+3] (A)
// and [64+4q..64+4q+3] (B) -> 256 B contiguous per quarter per load, all
// bytes used. Local 8-element argmax is pure VALU, scanned in increasing
// column order with strict '>' so ties keep the lowest index (jnp.argmax
// first-occurrence). Then only 4 butterfly steps (masks 1,2,4,8 stay inside
// the 16-lane group) x 2 shuffles = 2 DS ops/row.
// ---------------------------------------------------------------------------
__global__ void __launch_bounds__(256) argmax_conf_kernel(
    const float* __restrict__ y_pred,
    const int*   __restrict__ y_true,
    int*         __restrict__ conf,
    int n_rows)
{
    const int tid     = blockIdx.x * blockDim.x + threadIdx.x;
    const int lane    = threadIdx.x & 63;
    const int q       = lane & 15;        // lane within quarter
    const int quarter = (lane >> 4);      // which of 4 rows this wave iter
    const int wave    = tid >> 6;
    const int nwaves  = (gridDim.x * blockDim.x) >> 6;

    for (int base = wave * 4; base < n_rows; base += nwaves * 4) {
        const int row = base + quarter;

        float v   = -3.4e38f;
        int   idx = 0;

        if (row < n_rows) {
            const float4* rowp = (const float4*)(y_pred + (size_t)row * NC);
            const float4 a = rowp[q];        // cols 4q .. 4q+3
            const float4 b = rowp[q + 16];   // cols 64+4q .. 64+4q+3

            // In-order scan, strict > : lowest column wins ties.
            v = a.x; idx = 4 * q;
            if (a.y > v) { v = a.y; idx = 4 * q + 1; }
            if (a.z > v) { v = a.z; idx = 4 * q + 2; }
            if (a.w > v) { v = a.w; idx = 4 * q + 3; }
            if (b.x > v) { v = b.x; idx = 64 + 4 * q; }
            if (b.y > v) { v = b.y; idx = 64 + 4 * q + 1; }
            if (b.z > v) { v = b.z; idx = 64 + 4 * q + 2; }
            if (b.w > v) { v = b.w; idx = 64 + 4 * q + 3; }
        }

        // Butterfly within the 16-lane quarter (masks < 16 never cross it).
        #pragma unroll
        for (int off = 1; off < 16; off <<= 1) {
            float ov = __shfl_xor(v, off, 64);
            int   oi = __shfl_xor(idx, off, 64);
            if (ov > v || (ov == v && oi < idx)) { v = ov; idx = oi; }
        }

        if (q == 0 && row < n_rows) {
            const int t = y_true[row];
            atomicAdd(&conf[t * NC + idx], 1);
        }
    }
}

// ---------------------------------------------------------------------------
// Kernel 2: per-class F1 + mean, single 128-thread block.
// Faithful to the reference's gather-index quirk:
//   FP_c = (C-1)*conf[c,1] + conf[c,0]
//   FN_c = (C-1)*conf[1,c] + conf[0,c]
// ---------------------------------------------------------------------------
__global__ void f1_mean_kernel(const int* __restrict__ conf,
                               float* __restrict__ out)
{
    __shared__ float partial[NC];
    const int c = threadIdx.x;

    const float TP = (float)conf[c * NC + c];
    const float FP = (float)(NC - 1) * (float)conf[c * NC + 1] + (float)conf[c * NC + 0];
    const float FN = (float)(NC - 1) * (float)conf[1 * NC + c] + (float)conf[0 * NC + c];

    const float sens = TP / (TP + FN + EPSF);
    const float prec = TP / (TP + FP + EPSF);
    const float f1   = 2.0f * (prec * sens / (prec + sens + EPSF));

    partial[c] = f1;
    __syncthreads();

    #pragma unroll
    for (int s = 64; s > 0; s >>= 1) {
        if (c < s) partial[c] += partial[c + s];
        __syncthreads();
    }

    if (c == 0) out[0] = partial[0] / (float)NC;
}

extern "C" void kernel_launch(void* const* d_in, const int* in_sizes, int n_in,
                              void* d_out, int out_size, void* d_ws, size_t ws_size,
                              hipStream_t stream)
{
    const float* y_pred = (const float*)d_in[0];
    const int*   y_true = (const int*)d_in[1];
    float*       out    = (float*)d_out;
    int*         conf   = (int*)d_ws;   // 128*128*4 = 64 KB of scratch

    const int n_rows = in_sizes[1];     // N = 1048576

    // d_ws is poisoned to 0xAA before every timed call — zero the conf matrix.
    hipMemsetAsync(conf, 0, NC * NC * sizeof(int), stream);

    // 2048 blocks x 256 thr = 8192 waves x 4 rows/iter -> 32 iters/wave.
    // 8 blocks/CU x 4 waves = full 32-wave/CU occupancy (VGPR use is tiny).
    argmax_conf_kernel<<<2048, 256, 0, stream>>>(y_pred, y_true, conf, n_rows);

    f1_mean_kernel<<<1, NC, 0, stream>>>(conf, out);
}